// Round 2
// baseline (18909.827 us; speedup 1.0000x reference)
//
#include <hip/hip_runtime.h>
#include <cmath>

#define EIDN  30000
#define EMBN  256
#define HIDN  512
#define INDIM 3
#define SRCT  128
#define TRGT  50
#define BN    64
#define G3H   1536
#define WIH_PAD 260   // padded row length for W_ih_dec (257 -> 260, 16B-aligned rows)
#define NWG   512     // persistent grid: 2 blocks/CU x 256 CUs (guaranteed by launch_bounds+LDS)
#define GEMM_WGS 469  // ceil(30000/64)

struct alignas(16) WS {
  float wihd[G3H * WIH_PAD];        // padded W_ih_dec
  float hb[2][BN][HIDN];            // ping-pong hidden state
  float rowsum[BN];
  float rate_cur[BN];
  int   eid_cur[BN];
  unsigned long long amax[BN];
  int   bar;                        // global barrier counter (monotonic per launch)
};

// one LDS allocation shared by all phases (max = gemm: 34816 B -> >=2 blocks/CU)
union SMem {
  float encpart[BN][4][6];
  struct { float partx[BN][4][6]; float parth[BN][4][6]; } gru;
  struct { float sh[64][68]; float sw[64][68]; } gemm;
  struct { float cat[EMBN + HIDN]; float wsum[4]; float logs[BN]; } fin;
};

__device__ __forceinline__ float sigmoidf_(float x) { return 1.f / (1.f + expf(-x)); }

__device__ __forceinline__ unsigned int orderf_(float f) {
  unsigned int b = __float_as_uint(f);
  return b ^ ((b & 0x80000000u) ? 0xFFFFFFFFu : 0x80000000u);
}

__device__ __forceinline__ unsigned long long shfl_down_u64(unsigned long long v, int off, int w) {
  unsigned int lo = (unsigned int)v;
  unsigned int hi = (unsigned int)(v >> 32);
  lo = __shfl_down(lo, off, w);
  hi = __shfl_down(hi, off, w);
  return ((unsigned long long)hi << 32) | (unsigned long long)lo;
}

// hand-rolled grid barrier: monotonic counter, device-scope release/acquire.
// bar must be zeroed by k_init before k_run starts (stream-ordered).
__device__ __forceinline__ void gsync(int* bar, int& ph) {
  __syncthreads();
  if (threadIdx.x == 0) {
    ++ph;
    __hip_atomic_fetch_add(bar, 1, __ATOMIC_RELEASE, __HIP_MEMORY_SCOPE_AGENT);
    const int target = ph * NWG;
    int guard = 0;
    while (__hip_atomic_load(bar, __ATOMIC_RELAXED, __HIP_MEMORY_SCOPE_AGENT) < target) {
      __builtin_amdgcn_s_sleep(2);
      if (++guard > 20000000) break;   // failsafe: never hang the queue
    }
    (void)__hip_atomic_load(bar, __ATOMIC_ACQUIRE, __HIP_MEMORY_SCOPE_AGENT);
  }
  __syncthreads();
}

// 6 parallel dot-products (float4): acc[i] += dot(x[0..4n4), w[i][0..4n4))
__device__ __forceinline__ void dot6(const float* __restrict__ x,
                                     const float* const* __restrict__ w,
                                     int n4, float* __restrict__ acc) {
  const float4* x4 = (const float4*)x;
#pragma unroll 4
  for (int k = 0; k < n4; ++k) {
    float4 xv = x4[k];
#pragma unroll
    for (int i = 0; i < 6; ++i) {
      float4 wv = ((const float4*)w[i])[k];
      acc[i] = fmaf(xv.w, wv.w, fmaf(xv.z, wv.z, fmaf(xv.y, wv.y, fmaf(xv.x, wv.x, acc[i]))));
    }
  }
}

// ---------------------------------------------------------------- init/prep
__global__ __launch_bounds__(256) void k_init(const float* __restrict__ Wih_d,
                       const int* __restrict__ trg_eid,
                       const float* __restrict__ trg_rate,
                       float* __restrict__ out, WS* __restrict__ ws) {
  int gid = blockIdx.x * blockDim.x + threadIdx.x;
  int nt = gridDim.x * blockDim.x;
  // pad-copy W_ih_dec [1536][257] -> [1536][260]
  const int N = G3H * 257;
  for (int i = gid; i < N; i += nt) {
    int r = i / 257, c = i - r * 257;
    ws->wihd[r * WIH_PAD + c] = Wih_d[i];
  }
  float* hb0 = &ws->hb[0][0][0];
  for (int i = gid; i < BN * HIDN; i += nt) hb0[i] = 0.f;
  if (gid < BN) {
    ws->eid_cur[gid]  = trg_eid[gid];
    ws->rate_cur[gid] = trg_rate[gid];
    out[(size_t)TRGT * BN * EIDN + gid] = 0.f;  // rate_result row 0
  }
  if (gid == 0) ws->bar = 0;                    // reset grid barrier (re-entrant per replay)
  float4* o4 = (float4*)out;                    // eid_result t=0 slice = 0
  for (int f = gid; f < BN * EIDN / 4; f += nt) o4[f] = make_float4(0.f, 0.f, 0.f, 0.f);
}

// ---------------------------------------------------------------- encoder step body
// WGs 0..255: WG owns 2 hidden units (6 W_hh rows). thread = (b, k-quarter).
__device__ __forceinline__ void enc_step(SMem& sm,
    const float* __restrict__ src, const int* __restrict__ src_len,
    const float* __restrict__ Wih, const float* __restrict__ bih,
    const float* __restrict__ bhh, const float* __restrict__ Whh,
    const float* __restrict__ hin, float* __restrict__ hout, int t) {
  int tid = threadIdx.x;
  int b = tid & 63, kq = tid >> 6;
  int j0 = blockIdx.x * 2;

  const float* wrows[6];
#pragma unroll
  for (int idx = 0; idx < 6; ++idx) {
    int u = idx / 3, g = idx - 3 * u;
    wrows[idx] = Whh + (size_t)(g * HIDN + j0 + u) * HIDN + kq * 128;
  }
  float acc[6] = {0.f, 0.f, 0.f, 0.f, 0.f, 0.f};
  dot6(hin + b * HIDN + kq * 128, wrows, 32, acc);
#pragma unroll
  for (int idx = 0; idx < 6; ++idx) sm.encpart[b][kq][idx] = acc[idx];
  __syncthreads();

  if (kq == 0) {
    int len = src_len[b];
    const float* x = src + ((size_t)t * BN + b) * INDIM;
    float x0 = x[0], x1 = x[1], x2 = x[2];
#pragma unroll
    for (int u = 0; u < 2; ++u) {
      int j = j0 + u;
      float hg[3], ig[3];
#pragma unroll
      for (int g = 0; g < 3; ++g) {
        int idx = u * 3 + g;
        hg[g] = sm.encpart[b][0][idx] + sm.encpart[b][1][idx] + sm.encpart[b][2][idx]
                + sm.encpart[b][3][idx] + bhh[g * HIDN + j];
        int row = g * HIDN + j;
        ig[g] = bih[row] + x0 * Wih[row * 3] + x1 * Wih[row * 3 + 1] + x2 * Wih[row * 3 + 2];
      }
      float r = sigmoidf_(ig[0] + hg[0]);
      float z = sigmoidf_(ig[1] + hg[1]);
      float n = tanhf(ig[2] + r * hg[2]);
      float ho = hin[b * HIDN + j];
      hout[b * HIDN + j] = (t < len) ? ((1.f - z) * n + z * ho) : ho;
    }
  }
}

// ---------------------------------------------------------------- decoder GRU body
// WGs 0..255: WG owns 2 hidden units. K=769 split in 4 balanced slices across kq.
__device__ __forceinline__ void dec_gru(SMem& sm,
    const float* __restrict__ emb_dec, const float* __restrict__ Whh,
    const float* __restrict__ bih, const float* __restrict__ bhh,
    WS* __restrict__ ws, const float* __restrict__ hin, float* __restrict__ hout) {
  int tid = threadIdx.x;
  if (blockIdx.x == 0 && tid < BN) {   // reset reductions for upcoming GEMM phase
    ws->rowsum[tid] = 0.f;
    ws->amax[tid] = 0ULL;
  }
  int b = tid & 63, kq = tid >> 6;
  int j0 = blockIdx.x * 2;
  int eid = ws->eid_cur[b];
  const float* xe = emb_dec + (size_t)eid * EMBN;
  const float* hrow = hin + b * HIDN;

  float accx[6] = {0.f, 0.f, 0.f, 0.f, 0.f, 0.f};
  float acch[6] = {0.f, 0.f, 0.f, 0.f, 0.f, 0.f};
  const float* w[6];

  if (kq == 0) {            // emb[0,192)
#pragma unroll
    for (int idx = 0; idx < 6; ++idx) {
      int u = idx / 3, g = idx - 3 * u;
      w[idx] = ws->wihd + (size_t)(g * HIDN + j0 + u) * WIH_PAD;
    }
    dot6(xe, w, 48, accx);
  } else if (kq == 1) {     // emb[192,256) + rate + h[0,128)
    float rate = ws->rate_cur[b];
#pragma unroll
    for (int idx = 0; idx < 6; ++idx) {
      int u = idx / 3, g = idx - 3 * u;
      const float* wr = ws->wihd + (size_t)(g * HIDN + j0 + u) * WIH_PAD;
      w[idx] = wr + 192;
      accx[idx] = rate * wr[256];
    }
    dot6(xe + 192, w, 16, accx);
#pragma unroll
    for (int idx = 0; idx < 6; ++idx) {
      int u = idx / 3, g = idx - 3 * u;
      w[idx] = Whh + (size_t)(g * HIDN + j0 + u) * HIDN;
    }
    dot6(hrow, w, 32, acch);
  } else {                  // kq=2: h[128,320), kq=3: h[320,512)
    int off = (kq == 2) ? 128 : 320;
#pragma unroll
    for (int idx = 0; idx < 6; ++idx) {
      int u = idx / 3, g = idx - 3 * u;
      w[idx] = Whh + (size_t)(g * HIDN + j0 + u) * HIDN + off;
    }
    dot6(hrow + off, w, 48, acch);
  }
#pragma unroll
  for (int idx = 0; idx < 6; ++idx) {
    sm.gru.partx[b][kq][idx] = accx[idx];
    sm.gru.parth[b][kq][idx] = acch[idx];
  }
  __syncthreads();

  if (kq == 0) {
#pragma unroll
    for (int u = 0; u < 2; ++u) {
      int j = j0 + u;
      float ix[3], hh[3];
#pragma unroll
      for (int g = 0; g < 3; ++g) {
        int idx = u * 3 + g;
        ix[g] = sm.gru.partx[b][0][idx] + sm.gru.partx[b][1][idx] + sm.gru.partx[b][2][idx]
                + sm.gru.partx[b][3][idx] + bih[g * HIDN + j];
        hh[g] = sm.gru.parth[b][0][idx] + sm.gru.parth[b][1][idx] + sm.gru.parth[b][2][idx]
                + sm.gru.parth[b][3][idx] + bhh[g * HIDN + j];
      }
      float r = sigmoidf_(ix[0] + hh[0]);
      float z = sigmoidf_(ix[1] + hh[1]);
      float n = tanhf(ix[2] + r * hh[2]);
      hout[b * HIDN + j] = (1.f - z) * n + z * hin[b * HIDN + j];
    }
  }
}

// ---------------------------------------------------------------- rate head body
// WGs 0..63 (one per batch row), runs in phase C after amax/rowsum are final.
__device__ __forceinline__ void rate_head(SMem& sm,
    const float* __restrict__ emb_mt, const float* __restrict__ Wr1,
    const float* __restrict__ br1, const float* __restrict__ Wr2,
    const float* __restrict__ br2, const float* __restrict__ h,
    WS* __restrict__ ws, float* __restrict__ rate_out) {
  int tid = threadIdx.x;
  int b = blockIdx.x;
  int idx = (int)(0xFFFFFFFFu - (unsigned)(ws->amax[b] & 0xFFFFFFFFull));
  sm.fin.cat[tid]              = emb_mt[(size_t)idx * EMBN + tid];
  sm.fin.cat[EMBN + tid]       = h[b * HIDN + tid];
  sm.fin.cat[EMBN + 256 + tid] = h[b * HIDN + 256 + tid];
  __syncthreads();
  const float4* c4 = (const float4*)sm.fin.cat;
  int j0 = tid * 2;
  const float4* w0 = (const float4*)(Wr1 + (size_t)j0 * (EMBN + HIDN));
  const float4* w1 = (const float4*)(Wr1 + (size_t)(j0 + 1) * (EMBN + HIDN));
  float a0 = br1[j0], a1 = br1[j0 + 1];
#pragma unroll 4
  for (int k = 0; k < (EMBN + HIDN) / 4; ++k) {
    float4 cv = c4[k];
    float4 v0 = w0[k], v1 = w1[k];
    a0 = fmaf(cv.w, v0.w, fmaf(cv.z, v0.z, fmaf(cv.y, v0.y, fmaf(cv.x, v0.x, a0))));
    a1 = fmaf(cv.w, v1.w, fmaf(cv.z, v1.z, fmaf(cv.y, v1.y, fmaf(cv.x, v1.x, a1))));
  }
  float part = fmaxf(a0, 0.f) * Wr2[j0] + fmaxf(a1, 0.f) * Wr2[j0 + 1];
#pragma unroll
  for (int off = 32; off > 0; off >>= 1) part += __shfl_down(part, off, 64);
  if ((tid & 63) == 0) sm.fin.wsum[tid >> 6] = part;
  __syncthreads();
  if (tid == 0) {
    float tot = sm.fin.wsum[0] + sm.fin.wsum[1] + sm.fin.wsum[2] + sm.fin.wsum[3] + br2[0];
    float rt = sigmoidf_(tot);
    rate_out[b] = rt;
    ws->rate_cur[b] = rt;
    ws->eid_cur[b] = idx;
  }
}

// ---------------------------------------------------------------- the whole model, one launch
__global__ __launch_bounds__(256, 2) void k_run(
    const float* __restrict__ src, const int* __restrict__ src_len,
    const float* __restrict__ Wih_e, const float* __restrict__ Whh_e,
    const float* __restrict__ bih_e, const float* __restrict__ bhh_e,
    const float* __restrict__ emb_dec,
    const float* __restrict__ Whh_d, const float* __restrict__ bih_d,
    const float* __restrict__ bhh_d, const float* __restrict__ emb_mt,
    const float* __restrict__ Weid, const float* __restrict__ beid,
    const float* __restrict__ Wr1, const float* __restrict__ br1,
    const float* __restrict__ Wr2, const float* __restrict__ br2,
    float* __restrict__ out, WS* __restrict__ ws) {
  __shared__ SMem sm;
  const int w = blockIdx.x;
  const int tid = threadIdx.x;
  const int tr = tid >> 4, tc = tid & 15;
  int bphase = 0;

  // ---- encoder: 128 steps, 1 grid-sync each ----
  for (int t = 0; t < SRCT; ++t) {
    const float* hin = &ws->hb[t & 1][0][0];
    float* hout = &ws->hb[(t + 1) & 1][0][0];
    if (w < 256) enc_step(sm, src, src_len, Wih_e, bih_e, bhh_e, Whh_e, hin, hout, t);
    gsync(&ws->bar, bphase);
  }
  // final hidden is in hb[0]

  // ---- decoder: 49 steps, 3 grid-syncs each ----
  for (int s = 0; s < TRGT - 1; ++s) {
    const float* hin = &ws->hb[s & 1][0][0];
    float* hout = &ws->hb[(s + 1) & 1][0][0];

    // phase A: GRU cell (+ reset rowsum/amax for this step)
    if (w < 256) dec_gru(sm, emb_dec, Whh_d, bih_d, bhh_d, ws, hin, hout);
    gsync(&ws->bar, bphase);

    // phase B: one 64-col logits tile per WG; acc stays in registers across the sync
    float acc[4][4];
    bool full = false;
    const int c0 = w * 64;
    const int cbase = c0 + 4 * tc;
    if (w < GEMM_WGS) {
      full = (cbase + 3 < EIDN);
      const float* h = hout;
#pragma unroll
      for (int i = 0; i < 4; ++i)
#pragma unroll
        for (int m = 0; m < 4; ++m) acc[i][m] = 0.f;
      // reg-prefetch double-buffer: load tile kc into regs, write to LDS, prefetch kc+1,
      // compute kc. Hides global latency under the FMA loop.
      float4 hv[4], wv[4];
#pragma unroll
      for (int u = 0; u < 4; ++u) {
        int flat = tid + u * 256;
        int r = flat >> 4, k4 = flat & 15;
        hv[u] = *(const float4*)(h + r * HIDN + k4 * 4);
        int c = c0 + r;
        wv[u] = make_float4(0.f, 0.f, 0.f, 0.f);
        if (c < EIDN) wv[u] = *(const float4*)(Weid + (size_t)c * HIDN + k4 * 4);
      }
      for (int kc = 0; kc < 8; ++kc) {
#pragma unroll
        for (int u = 0; u < 4; ++u) {
          int flat = tid + u * 256;
          int r = flat >> 4, k4 = flat & 15;
          sm.gemm.sh[k4 * 4 + 0][r] = hv[u].x; sm.gemm.sh[k4 * 4 + 1][r] = hv[u].y;
          sm.gemm.sh[k4 * 4 + 2][r] = hv[u].z; sm.gemm.sh[k4 * 4 + 3][r] = hv[u].w;
          sm.gemm.sw[k4 * 4 + 0][r] = wv[u].x; sm.gemm.sw[k4 * 4 + 1][r] = wv[u].y;
          sm.gemm.sw[k4 * 4 + 2][r] = wv[u].z; sm.gemm.sw[k4 * 4 + 3][r] = wv[u].w;
        }
        __syncthreads();
        if (kc < 7) {
          int k0 = (kc + 1) * 64;
#pragma unroll
          for (int u = 0; u < 4; ++u) {
            int flat = tid + u * 256;
            int r = flat >> 4, k4 = flat & 15;
            hv[u] = *(const float4*)(h + r * HIDN + k0 + k4 * 4);
            int c = c0 + r;
            wv[u] = make_float4(0.f, 0.f, 0.f, 0.f);
            if (c < EIDN) wv[u] = *(const float4*)(Weid + (size_t)c * HIDN + k0 + k4 * 4);
          }
        }
#pragma unroll 8
        for (int kk = 0; kk < 64; ++kk) {
          float4 av = *(const float4*)&sm.gemm.sh[kk][4 * tr];
          float4 bv = *(const float4*)&sm.gemm.sw[kk][4 * tc];
          acc[0][0] = fmaf(av.x, bv.x, acc[0][0]); acc[0][1] = fmaf(av.x, bv.y, acc[0][1]);
          acc[0][2] = fmaf(av.x, bv.z, acc[0][2]); acc[0][3] = fmaf(av.x, bv.w, acc[0][3]);
          acc[1][0] = fmaf(av.y, bv.x, acc[1][0]); acc[1][1] = fmaf(av.y, bv.y, acc[1][1]);
          acc[1][2] = fmaf(av.y, bv.z, acc[1][2]); acc[1][3] = fmaf(av.y, bv.w, acc[1][3]);
          acc[2][0] = fmaf(av.z, bv.x, acc[2][0]); acc[2][1] = fmaf(av.z, bv.y, acc[2][1]);
          acc[2][2] = fmaf(av.z, bv.z, acc[2][2]); acc[2][3] = fmaf(av.z, bv.w, acc[2][3]);
          acc[3][0] = fmaf(av.w, bv.x, acc[3][0]); acc[3][1] = fmaf(av.w, bv.y, acc[3][1]);
          acc[3][2] = fmaf(av.w, bv.z, acc[3][2]); acc[3][3] = fmaf(av.w, bv.w, acc[3][3]);
        }
        __syncthreads();
      }
      float sume[4] = {0.f, 0.f, 0.f, 0.f};
      unsigned long long key[4] = {0ULL, 0ULL, 0ULL, 0ULL};
      if (full) {
        float4 bb = *(const float4*)(beid + cbase);
#pragma unroll
        for (int i = 0; i < 4; ++i) {
          acc[i][0] += bb.x; acc[i][1] += bb.y; acc[i][2] += bb.z; acc[i][3] += bb.w;
          sume[i] = expf(acc[i][0]) + expf(acc[i][1]) + expf(acc[i][2]) + expf(acc[i][3]);
#pragma unroll
          for (int cc = 0; cc < 4; ++cc) {
            unsigned long long pk = ((unsigned long long)orderf_(acc[i][cc]) << 32) |
                                    (unsigned long long)(0xFFFFFFFFu - (unsigned)(cbase + cc));
            if (pk > key[i]) key[i] = pk;
          }
        }
      }
#pragma unroll
      for (int off = 8; off > 0; off >>= 1) {
#pragma unroll
        for (int i = 0; i < 4; ++i) {
          sume[i] += __shfl_down(sume[i], off, 16);
          unsigned long long o = shfl_down_u64(key[i], off, 16);
          if (o > key[i]) key[i] = o;
        }
      }
      if (tc == 0) {
#pragma unroll
        for (int i = 0; i < 4; ++i) {
          int r = 4 * tr + i;
          atomicAdd(&ws->rowsum[r], sume[i]);
          atomicMax(&ws->amax[r], key[i]);
        }
      }
    }
    gsync(&ws->bar, bphase);

    // phase C: fused log-softmax store (single write, no re-read) + rate head
    float* oslice = out + (size_t)(s + 1) * BN * EIDN;
    if (w < GEMM_WGS) {
      if (tid < BN) sm.fin.logs[tid] = logf(ws->rowsum[tid]);
      __syncthreads();
      if (full) {
#pragma unroll
        for (int i = 0; i < 4; ++i) {
          float lb = sm.fin.logs[4 * tr + i];
          float4 L = make_float4(acc[i][0] - lb, acc[i][1] - lb, acc[i][2] - lb, acc[i][3] - lb);
          *(float4*)(oslice + (size_t)(4 * tr + i) * EIDN + cbase) = L;
        }
      }
    }
    if (w < BN)
      rate_head(sm, emb_mt, Wr1, br1, Wr2, br2, hout, ws,
                out + (size_t)TRGT * BN * EIDN + (size_t)(s + 1) * BN);
    gsync(&ws->bar, bphase);
  }
}

// ---------------------------------------------------------------- launcher
extern "C" void kernel_launch(void* const* d_in, const int* in_sizes, int n_in,
                              void* d_out, int out_size, void* d_ws, size_t ws_size,
                              hipStream_t stream) {
  const float* src      = (const float*)d_in[0];
  const int*   src_len  = (const int*)d_in[1];
  const int*   trg_eid  = (const int*)d_in[2];
  const float* trg_rate = (const float*)d_in[3];
  const float* Wih_e    = (const float*)d_in[4];
  const float* Whh_e    = (const float*)d_in[5];
  const float* bih_e    = (const float*)d_in[6];
  const float* bhh_e    = (const float*)d_in[7];
  const float* emb_dec  = (const float*)d_in[8];
  const float* Wih_d    = (const float*)d_in[9];
  const float* Whh_d    = (const float*)d_in[10];
  const float* bih_d    = (const float*)d_in[11];
  const float* bhh_d    = (const float*)d_in[12];
  const float* emb_mt   = (const float*)d_in[13];
  const float* Weid     = (const float*)d_in[14];
  const float* beid     = (const float*)d_in[15];
  const float* Wr1      = (const float*)d_in[16];
  const float* br1      = (const float*)d_in[17];
  const float* Wr2      = (const float*)d_in[18];
  const float* br2      = (const float*)d_in[19];
  float* out = (float*)d_out;

  WS* ws = (ws_size >= sizeof(WS)) ? (WS*)d_ws : (WS*)d_out;

  hipLaunchKernelGGL(k_init, dim3(256), dim3(256), 0, stream,
                     Wih_d, trg_eid, trg_rate, out, ws);
  hipLaunchKernelGGL(k_run, dim3(NWG), dim3(256), 0, stream,
                     src, src_len, Wih_e, Whh_e, bih_e, bhh_e,
                     emb_dec, Whh_d, bih_d, bhh_d, emb_mt,
                     Weid, beid, Wr1, br1, Wr2, br2, out, ws);
}